// Round 19
// baseline (196.634 us; speedup 1.0000x reference)
//
#include <hip/hip_runtime.h>

#define NN 1024
#define DD 64
#define CAP 96
#define RCAP 128
#define SENT 32768   // (1024<<5): decodes to G row 1024 = the ZERO dummy row
#define NL2E -1.44269504088896f

typedef __attribute__((ext_vector_type(8))) short bf16x8;
typedef __attribute__((ext_vector_type(4))) float f32x4;

// ---- device-global scratch (rewritten every call) ----
__device__ uint4    WnFragD[8*64];    // MFMA B-fragments: (s*4+t)*64 + lane
__device__ float    FSd[NN*DD];
__device__ float    Gd[NN*DD];
__device__ float    preBaseD[NN*DD];
__device__ float    fpreD[NN*DD];
__device__ float4   nodeDatD[NN*DD];  // {fs2n, preB2, civ, cf2}
__device__ int      lowNeiD[NN*CAP + 64];  // (j<<5) codes, SENT-padded
__device__ int      revNeiD[NN*RCAP];
__device__ int      revCntD[NN];
__device__ int2     hdrD[NN];
__device__ int      posArr[NN];
__device__ float    invNumD[NN];

__device__ __forceinline__ float sigm(float x)  { return 1.0f / (1.0f + __expf(-x)); }
__device__ __forceinline__ float tanhf_(float x){ return 2.0f / (1.0f + __expf(-2.0f*x)) - 1.0f; }
__device__ __forceinline__ unsigned short bf16r(float x) {
  unsigned u = __float_as_uint(x);
  u = u + 0x7fffu + ((u >> 16) & 1u);
  return (unsigned short)(u >> 16);
}

// ---- K1: per-node GEMV precompute (direct weight reads) + merged prep work ----
__global__ __launch_bounds__(256) void k_node(const int* __restrict__ seq,
                                              const float* __restrict__ numNei,
                                              const float* __restrict__ inputs,
                                              const float* __restrict__ h0,
                                              const float* __restrict__ Wg,
                                              const float* __restrict__ bg,
                                              const float* __restrict__ Ws,
                                              const float* __restrict__ bs,
                                              const float* __restrict__ Wn) {
  __shared__ float x_l[4][64];
  __shared__ float hh_l[4][64];
  int tid = threadIdx.x;
  int gid = blockIdx.x * 256 + tid;
  if (gid < NN) { posArr[seq[gid]] = gid; invNumD[gid] = 1.0f / numNei[gid]; revCntD[gid] = 0; }
  if (gid < 512) {   // pack Wn MFMA B-fragments
    int st = gid >> 6, lane = gid & 63;
    int s = st >> 2, t = st & 3;
    int row = 16*t + (lane & 15);
    int k0 = 32*s + 8*(lane >> 4);
    const float* wr = &Wn[row*64 + k0];
    uint4 f;
    f.x = (unsigned)bf16r(wr[0]) | ((unsigned)bf16r(wr[1]) << 16);
    f.y = (unsigned)bf16r(wr[2]) | ((unsigned)bf16r(wr[3]) << 16);
    f.z = (unsigned)bf16r(wr[4]) | ((unsigned)bf16r(wr[5]) << 16);
    f.w = (unsigned)bf16r(wr[6]) | ((unsigned)bf16r(wr[7]) << 16);
    WnFragD[st*64 + lane] = f;
  }
  for (int e2 = gid; e2 < NN*CAP; e2 += 256*256) lowNeiD[e2] = SENT;
  // per-node GEMV: thread d streams weight row d contiguously
  int w = tid >> 6, d = tid & 63;
  int i = blockIdx.x * 4 + w;
  x_l[w][d]  = inputs[i*DD + d];
  hh_l[w][d] = h0[i*DD + d];
  __syncthreads();
  float afs = bs[d], apre = bg[d], ag0 = 0.0f;
  const float4* wsr = (const float4*)&Ws[d*64];
  const float4* wnr = (const float4*)&Wn[d*64];
  const float4* wga = (const float4*)&Wg[d*128];
  const float4* wgb = (const float4*)&Wg[d*128 + 64];
  #pragma unroll 4
  for (int k4 = 0; k4 < 16; ++k4) {
    float4 ws4 = wsr[k4], wn4 = wnr[k4], wa4 = wga[k4], wb4 = wgb[k4];
    const float* wsp = (const float*)&ws4;
    const float* wnp = (const float*)&wn4;
    const float* wap = (const float*)&wa4;
    const float* wbp = (const float*)&wb4;
    #pragma unroll
    for (int j = 0; j < 4; ++j) {
      int k = 4*k4 + j;
      float xk = x_l[w][k], hk = hh_l[w][k];
      afs  += xk * wsp[j];
      ag0  += hk * wnp[j];
      apre += xk * wap[j] + hk * wbp[j];
    }
  }
  FSd[i*DD + d]      = afs;
  Gd[i*DD + d]       = ag0;
  preBaseD[i*DD + d] = apre;
  fpreD[i*DD + d]    = sigm(afs + ag0);
}

// ---- K2: split neighbors; fold future; LANE-PARALLEL reverse-edge scatter ----
__global__ __launch_bounds__(256) void k_edges(const float* __restrict__ adj,
                                               const float* __restrict__ c0) {
  int tid = threadIdx.x;
  int w = tid >> 6, d = tid & 63;   // d is also this thread's lane id
  int i = blockIdx.x * 4 + w;
  int pi = posArr[i];
  float fs = FSd[i*DD + d];
  float accP = 0.0f, accS = 0.0f;
  int cnt = 0;
  int myj = -1;                     // lane n captures the n-th lower neighbor
  for (int base = 0; base < NN; base += 64) {
    float a = adj[i*NN + base + d];
    unsigned long long mask = __ballot(a != 0.0f);
    while (mask) {
      int b = __ffsll(mask) - 1;
      mask &= (mask - 1);
      int j = base + b;
      if (posArr[j] < pi) {
        if (cnt == d) myj = j;      // uniform cnt, per-lane capture
        cnt++;
      } else {
        float g = Gd[j*DD + d];
        accP += g;
        accS += sigm(fs + g);
      }
    }
  }
  int ccap = (cnt < 64) ? cnt : 64;
  // parallel scatter: one memory latency instead of ~cnt serialized round-trips
  if (d < ccap) {
    lowNeiD[i*CAP + d] = myj << 5;
    int slot = atomicAdd(&revCntD[myj], 1);
    if (slot < RCAP) revNeiD[myj*RCAP + slot] = i;
  }
  float inv = invNumD[i];
  if (d == 0) hdrD[i] = make_int2(ccap, __float_as_int(inv));
  float c0v = c0[i*DD + d];
  float civ = c0v * inv;
  nodeDatD[i*DD + d] = make_float4(NL2E * fs,                 // fs2n = -fs*log2e
                                   preBaseD[i*DD + d] + accP * inv,
                                   civ,
                                   c0v * fpreD[i*DD + d] + civ * accS);
}

// ---- K3: dataflow scheduler; keep-one with PREDICTED keeper (peek countdown==1) ----
__global__ __launch_bounds__(1024, 4) void k_seq(float* __restrict__ out) {
  __shared__ unsigned long long Gl64[(NN*DD + 64)/4];  // bf16 G rows + ZERO dummy row
  __shared__ unsigned low8p[NN][4];
  __shared__ int      queue_[NN];            // packed {node|cnt<<10|rcnt<<17}
  __shared__ int      indeg[NN];             // countdown | cnt<<8 | rcnt<<15
  __shared__ float    invL[NN];
  __shared__ unsigned short hstage[16][64];
  __shared__ int head, tail, doneCnt;
  unsigned short* Gl = (unsigned short*)Gl64;
  int tid  = threadIdx.x;
  int lane = tid & 63, w = tid >> 6;
  if (tid == 0) { head = 0; tail = 0; doneCnt = 0; }
  queue_[tid] = -1;
  int2 hdr = hdrD[tid];
  int  rc  = revCntD[tid];
  int  cnt0 = hdr.x;
  indeg[tid] = cnt0 | (cnt0 << 8) | (rc << 15);
  invL[tid]  = __int_as_float(hdr.y);
  {
    uint4 a = *(const uint4*)&lowNeiD[tid*CAP];
    uint4 b = *(const uint4*)&lowNeiD[tid*CAP + 4];
    low8p[tid][0] = (a.x & 0xffffu) | (a.y << 16);
    low8p[tid][1] = (a.z & 0xffffu) | (a.w << 16);
    low8p[tid][2] = (b.x & 0xffffu) | (b.y << 16);
    low8p[tid][3] = (b.z & 0xffffu) | (b.w << 16);
  }
  if (tid < 16) Gl64[NN*DD/4 + tid] = 0ull;    // ZERO dummy row
  uint4 fb[2][4];
  #pragma unroll
  for (int s = 0; s < 2; ++s) {
    #pragma unroll
    for (int t = 0; t < 4; ++t)
      fb[s][t] = WnFragD[(s*4 + t)*64 + lane];
  }
  __syncthreads();
  if (cnt0 == 0) {
    int p = __hip_atomic_fetch_add(&tail, 1, __ATOMIC_RELAXED, __HIP_MEMORY_SCOPE_WORKGROUP);
    __hip_atomic_store(&queue_[p], tid | (rc << 17), __ATOMIC_RELEASE, __HIP_MEMORY_SCOPE_WORKGROUP);
  }
  __syncthreads();

  // claim first ticket; blocking pop
  int t0 = 0;
  if (lane == 0) t0 = __hip_atomic_fetch_add(&head, 1, __ATOMIC_RELAXED, __HIP_MEMORY_SCOPE_WORKGROUP);
  int t = __builtin_amdgcn_readfirstlane(t0);
  int e = -1;
  if (t < NN) {
    e = __hip_atomic_load(&queue_[t], __ATOMIC_ACQUIRE, __HIP_MEMORY_SCOPE_WORKGROUP);
    while (e < 0)
      e = __hip_atomic_load(&queue_[t], __ATOMIC_ACQUIRE, __HIP_MEMORY_SCOPE_WORKGROUP);
  } else {
    return;  // never for 16 waves, NN >= 16
  }
  e = __builtin_amdgcn_readfirstlane(e);

  int    i, cnt, rcnt, jb2v, r0, r1;
  float4 nd;
  float  inv;
  uint4  lvv;
  #define ISSUE(E) do {                                               \
    i    = (E) & 1023;                                                \
    cnt  = ((E) >> 10) & 127;                                         \
    rcnt = ((E) >> 17) & 255;                                         \
    nd   = nodeDatD[i*DD + lane];                                     \
    jb2v = lowNeiD[i*CAP + 8 + lane];                                 \
    r0   = (lane < rcnt)      ? revNeiD[i*RCAP + lane]      : -1;     \
    r1   = (lane + 64 < rcnt) ? revNeiD[i*RCAP + 64 + lane] : -1;     \
    inv  = invL[i];                                                   \
    lvv  = *(uint4*)&low8p[i][0];                                     \
  } while (0)
  ISSUE(e);

  for (;;) {
    float fs2n = nd.x;
    float accG = 0.0f, accS = 0.0f;
    // ---- gather: 4-granular static blocks; all reads first, then grouped math ----
    float g[32];
    #define LD(c) __uint_as_float(((unsigned)Gl[((c) << 1) + lane]) << 16)
    if (cnt > 0) {
      g[0]=LD(lvv.x & 0xffffu); g[1]=LD(lvv.x >> 16);
      g[2]=LD(lvv.y & 0xffffu); g[3]=LD(lvv.y >> 16);
    }
    if (cnt > 4) {
      g[4]=LD(lvv.z & 0xffffu); g[5]=LD(lvv.z >> 16);
      g[6]=LD(lvv.w & 0xffffu); g[7]=LD(lvv.w >> 16);
    }
    if (cnt > 8) {
      #pragma unroll
      for (int q = 0; q < 4; ++q) g[8+q]  = LD(__builtin_amdgcn_readlane(jb2v, q));
    }
    if (cnt > 12) {
      #pragma unroll
      for (int q = 0; q < 4; ++q) g[12+q] = LD(__builtin_amdgcn_readlane(jb2v, 4+q));
    }
    if (cnt > 16) {
      #pragma unroll
      for (int q = 0; q < 4; ++q) g[16+q] = LD(__builtin_amdgcn_readlane(jb2v, 8+q));
    }
    if (cnt > 20) {
      #pragma unroll
      for (int q = 0; q < 4; ++q) g[20+q] = LD(__builtin_amdgcn_readlane(jb2v, 12+q));
    }
    if (cnt > 24) {
      #pragma unroll
      for (int q = 0; q < 4; ++q) g[24+q] = LD(__builtin_amdgcn_readlane(jb2v, 16+q));
    }
    if (cnt > 28) {
      #pragma unroll
      for (int q = 0; q < 4; ++q) g[28+q] = LD(__builtin_amdgcn_readlane(jb2v, 20+q));
    }
    // quad: sum of 4 sigmoids with ONE rcp
    auto quad = [&](float ga, float gb, float gc, float gd) {
      float xa = fminf(__builtin_fmaf(ga, NL2E, fs2n), 25.0f);
      float xb = fminf(__builtin_fmaf(gb, NL2E, fs2n), 25.0f);
      float xc = fminf(__builtin_fmaf(gc, NL2E, fs2n), 25.0f);
      float xd = fminf(__builtin_fmaf(gd, NL2E, fs2n), 25.0f);
      float ea = __builtin_amdgcn_exp2f(xa);
      float eb = __builtin_amdgcn_exp2f(xb);
      float ec = __builtin_amdgcn_exp2f(xc);
      float ed = __builtin_amdgcn_exp2f(xd);
      float s0 = ea + eb, n0 = s0 + 2.0f;
      float d0 = __builtin_fmaf(ea, eb, s0) + 1.0f;
      float s1 = ec + ed, n1 = s1 + 2.0f;
      float d1 = __builtin_fmaf(ec, ed, s1) + 1.0f;
      float Nn = __builtin_fmaf(n0, d1, n1 * d0);
      float Dd = d0 * d1;
      accS = __builtin_fmaf(Nn, __builtin_amdgcn_rcpf(Dd), accS);
      accG += (ga + gb) + (gc + gd);
    };
    if (cnt > 0)  quad(g[0],  g[1],  g[2],  g[3]);
    if (cnt > 4)  quad(g[4],  g[5],  g[6],  g[7]);
    if (cnt > 8)  quad(g[8],  g[9],  g[10], g[11]);
    if (cnt > 12) quad(g[12], g[13], g[14], g[15]);
    if (cnt > 16) quad(g[16], g[17], g[18], g[19]);
    if (cnt > 20) quad(g[20], g[21], g[22], g[23]);
    if (cnt > 24) quad(g[24], g[25], g[26], g[27]);
    if (cnt > 28) quad(g[28], g[29], g[30], g[31]);
    if (cnt > 32) {
      for (int base = 32; base < cnt; base += 4) {
        float ga = LD(__builtin_amdgcn_readlane(jb2v, base - 8));
        float gb = LD(__builtin_amdgcn_readlane(jb2v, base - 7));
        float gc = LD(__builtin_amdgcn_readlane(jb2v, base - 6));
        float gd = LD(__builtin_amdgcn_readlane(jb2v, base - 5));
        quad(ga, gb, gc, gd);
      }
    }
    // pad correction: pads read the zero row -> each added sigm(fs) to accS
    {
      int slots = (cnt <= 32) ? ((cnt + 3) & ~3) : (32 + ((cnt - 32 + 3) & ~3));
      float e0   = __builtin_amdgcn_exp2f(fminf(fs2n, 25.0f));
      float sig0 = __builtin_amdgcn_rcpf(1.0f + e0);
      accS -= (float)(slots - cnt) * sig0;
    }
    float pre = nd.y + inv * accG;
    float is  = sigm(pre);
    float hcl = tanhf_(pre);
    float c   = nd.z * accS + nd.w + is * hcl;
    float h   = tanhf_(is * c);
    // save current node's tail state before ISSUE overwrites
    int ic = i, r0c = r0, r1c = r1;
    // ---- keeper PREDICTION via relaxed peek: countdown==1 means WE are the only
    // remaining producer (each producer decrements once) -> guaranteed keeper.
    // No decrement happens here; publish-then-RMW ordering below is unchanged. ----
    int w0 = (r0c >= 0) ? __hip_atomic_load(&indeg[r0c], __ATOMIC_RELAXED, __HIP_MEMORY_SCOPE_WORKGROUP) : 0;
    int w1 = (r1c >= 0) ? __hip_atomic_load(&indeg[r1c], __ATOMIC_RELAXED, __HIP_MEMORY_SCOPE_WORKGROUP) : 0;
    unsigned long long pm0 = __ballot((r0c >= 0) && ((w0 & 0xff) == 1));
    unsigned long long pm1 = __ballot((r1c >= 0) && ((w1 & 0xff) == 1));
    int ks = -1, kl = -1, keepEn = -1;
    if (pm0) {
      kl = __ffsll(pm0) - 1; ks = 0;
      int rr = __builtin_amdgcn_readlane(r0c, kl);
      int ww = __builtin_amdgcn_readlane(w0, kl);
      keepEn = rr | (((ww >> 8) & 127) << 10) | (((ww >> 15) & 255) << 17);
    } else if (pm1) {
      kl = __ffsll(pm1) - 1; ks = 1;
      int rr = __builtin_amdgcn_readlane(r1c, kl);
      int ww = __builtin_amdgcn_readlane(w1, kl);
      keepEn = rr | (((ww >> 8) & 127) << 10) | (((ww >> 15) & 255) << 17);
    }
    bool kept = (keepEn >= 0);
    if (kept) ISSUE(keepEn);   // predicted keeper's loads fly UNDER the MFMA tail
    // ---- G[ic] = h @ Wn^T on the MFMA pipe; publish ----
    hstage[w][lane] = bf16r(h);
    const uint4* hv = (const uint4*)&hstage[w][0];
    uint4 fa0 = hv[lane >> 4];
    uint4 fa1 = hv[4 + (lane >> 4)];
    f32x4 z = {0.f, 0.f, 0.f, 0.f};
    f32x4 a0 = __builtin_amdgcn_mfma_f32_16x16x32_bf16(__builtin_bit_cast(bf16x8, fa0), __builtin_bit_cast(bf16x8, fb[0][0]), z, 0, 0, 0);
    f32x4 a1 = __builtin_amdgcn_mfma_f32_16x16x32_bf16(__builtin_bit_cast(bf16x8, fa0), __builtin_bit_cast(bf16x8, fb[0][1]), z, 0, 0, 0);
    f32x4 a2 = __builtin_amdgcn_mfma_f32_16x16x32_bf16(__builtin_bit_cast(bf16x8, fa0), __builtin_bit_cast(bf16x8, fb[0][2]), z, 0, 0, 0);
    f32x4 a3 = __builtin_amdgcn_mfma_f32_16x16x32_bf16(__builtin_bit_cast(bf16x8, fa0), __builtin_bit_cast(bf16x8, fb[0][3]), z, 0, 0, 0);
    a0 = __builtin_amdgcn_mfma_f32_16x16x32_bf16(__builtin_bit_cast(bf16x8, fa1), __builtin_bit_cast(bf16x8, fb[1][0]), a0, 0, 0, 0);
    a1 = __builtin_amdgcn_mfma_f32_16x16x32_bf16(__builtin_bit_cast(bf16x8, fa1), __builtin_bit_cast(bf16x8, fb[1][1]), a1, 0, 0, 0);
    a2 = __builtin_amdgcn_mfma_f32_16x16x32_bf16(__builtin_bit_cast(bf16x8, fa1), __builtin_bit_cast(bf16x8, fb[1][2]), a2, 0, 0, 0);
    a3 = __builtin_amdgcn_mfma_f32_16x16x32_bf16(__builtin_bit_cast(bf16x8, fa1), __builtin_bit_cast(bf16x8, fb[1][3]), a3, 0, 0, 0);
    float r01 = (lane & 16) ? a1[0] : a0[0];
    float r23 = (lane & 16) ? a3[0] : a2[0];
    float rg  = (lane & 32) ? r23 : r01;
    Gl[(ic << 6) + lane] = bf16r(rg);        // publish
    // ---- notify RMWs AFTER publish (R17 release-sequence semantics) ----
    int en0 = -1, en1 = -1;
    if (r0c >= 0) {
      int old = __hip_atomic_fetch_add(&indeg[r0c], -1, __ATOMIC_ACQ_REL, __HIP_MEMORY_SCOPE_WORKGROUP);
      if ((old & 0xff) == 1)
        en0 = r0c | (((old >> 8) & 127) << 10) | (((old >> 15) & 255) << 17);
    }
    if (r1c >= 0) {
      int old = __hip_atomic_fetch_add(&indeg[r1c], -1, __ATOMIC_ACQ_REL, __HIP_MEMORY_SCOPE_WORKGROUP);
      if ((old & 0xff) == 1)
        en1 = r1c | (((old >> 8) & 127) << 10) | (((old >> 15) & 255) << 17);
    }
    if (!kept) {   // prediction missed: late keeper selection (R17 path)
      unsigned long long m0 = __ballot(en0 >= 0);
      unsigned long long m1 = __ballot(en1 >= 0);
      if (m0) {
        kl = __ffsll(m0) - 1; ks = 0;
        keepEn = __builtin_amdgcn_readlane(en0, kl);
      } else if (m1) {
        kl = __ffsll(m1) - 1; ks = 1;
        keepEn = __builtin_amdgcn_readlane(en1, kl);
      }
      if (keepEn >= 0) { kept = true; ISSUE(keepEn); }
    }
    if (en0 >= 0 && !(ks == 0 && lane == kl)) {
      int p = __hip_atomic_fetch_add(&tail, 1, __ATOMIC_RELAXED, __HIP_MEMORY_SCOPE_WORKGROUP);
      __hip_atomic_store(&queue_[p], en0, __ATOMIC_RELEASE, __HIP_MEMORY_SCOPE_WORKGROUP);
    }
    if (en1 >= 0 && !(ks == 1 && lane == kl)) {
      int p = __hip_atomic_fetch_add(&tail, 1, __ATOMIC_RELAXED, __HIP_MEMORY_SCOPE_WORKGROUP);
      __hip_atomic_store(&queue_[p], en1, __ATOMIC_RELEASE, __HIP_MEMORY_SCOPE_WORKGROUP);
    }
    if (lane == 0)
      __hip_atomic_fetch_add(&doneCnt, 1, __ATOMIC_RELAXED, __HIP_MEMORY_SCOPE_WORKGROUP);
    out[ic*DD + lane] = 2.0f * h;
    if (kept) continue;        // keeper proceeds directly; ISSUE already in flight
    // ---- pop path (off the critical chain): claim ticket, spin, doneCnt exit ----
    if (lane == 0) t0 = __hip_atomic_fetch_add(&head, 1, __ATOMIC_RELAXED, __HIP_MEMORY_SCOPE_WORKGROUP);
    t = __builtin_amdgcn_readfirstlane(t0);
    if (t >= NN) break;
    int e3;
    for (;;) {
      e3 = __hip_atomic_load(&queue_[t], __ATOMIC_ACQUIRE, __HIP_MEMORY_SCOPE_WORKGROUP);
      if (e3 >= 0) break;
      if (__hip_atomic_load(&doneCnt, __ATOMIC_RELAXED, __HIP_MEMORY_SCOPE_WORKGROUP) == NN) break;
    }
    if (e3 < 0) break;
    e3 = __builtin_amdgcn_readfirstlane(e3);
    ISSUE(e3);
  }
  #undef LD
  #undef ISSUE
}

extern "C" void kernel_launch(void* const* d_in, const int* in_sizes, int n_in,
                              void* d_out, int out_size, void* d_ws, size_t ws_size,
                              hipStream_t stream) {
  const float* inputs = (const float*)d_in[0];
  const float* adj    = (const float*)d_in[1];
  const float* numNei = (const float*)d_in[2];
  const float* h0     = (const float*)d_in[3];
  const float* c0     = (const float*)d_in[4];
  const float* Wg     = (const float*)d_in[5];
  const float* bg     = (const float*)d_in[6];
  const float* Ws     = (const float*)d_in[7];
  const float* bs     = (const float*)d_in[8];
  const float* Wn     = (const float*)d_in[9];
  const int*   seq    = (const int*)d_in[10];
  float* out = (float*)d_out;

  k_node <<<256, 256, 0, stream>>>(seq, numNei, inputs, h0, Wg, bg, Ws, bs, Wn);
  k_edges<<<256, 256, 0, stream>>>(adj, c0);
  k_seq  <<<1, 1024, 0, stream>>>(out);
}

// Round 20
// 181.699 us; speedup vs baseline: 1.0822x; 1.0822x over previous
//
#include <hip/hip_runtime.h>

#define NN 1024
#define DD 64
#define CAP 96
#define RCAP 128
#define SENT 32768   // (1024<<5): decodes to G row 1024 = the ZERO dummy row
#define NL2E -1.44269504088896f

typedef __attribute__((ext_vector_type(8))) short bf16x8;
typedef __attribute__((ext_vector_type(4))) float f32x4;

// ---- device-global scratch (rewritten every call) ----
__device__ uint4    WnFragD[8*64];    // MFMA B-fragments: (s*4+t)*64 + lane
__device__ float    FSd[NN*DD];
__device__ float    Gd[NN*DD];
__device__ float    preBaseD[NN*DD];
__device__ float    fpreD[NN*DD];
__device__ float4   nodeDatD[NN*DD];  // {fs2n, preB2, civ, cf2}
__device__ int      lowNeiD[NN*CAP + 64];  // (j<<5) codes, SENT-padded
__device__ int      revNeiD[NN*RCAP];
__device__ int      revCntD[NN];
__device__ int2     hdrD[NN];
__device__ int      posArr[NN];
__device__ float    invNumD[NN];

__device__ __forceinline__ float sigm(float x)  { return 1.0f / (1.0f + __expf(-x)); }
__device__ __forceinline__ float tanhf_(float x){ return 2.0f / (1.0f + __expf(-2.0f*x)) - 1.0f; }
__device__ __forceinline__ unsigned short bf16r(float x) {
  unsigned u = __float_as_uint(x);
  u = u + 0x7fffu + ((u >> 16) & 1u);
  return (unsigned short)(u >> 16);
}

// ---- K1: per-node GEMV precompute (direct weight reads) + merged prep work ----
__global__ __launch_bounds__(256) void k_node(const int* __restrict__ seq,
                                              const float* __restrict__ numNei,
                                              const float* __restrict__ inputs,
                                              const float* __restrict__ h0,
                                              const float* __restrict__ Wg,
                                              const float* __restrict__ bg,
                                              const float* __restrict__ Ws,
                                              const float* __restrict__ bs,
                                              const float* __restrict__ Wn) {
  __shared__ float x_l[4][64];
  __shared__ float hh_l[4][64];
  int tid = threadIdx.x;
  int gid = blockIdx.x * 256 + tid;
  if (gid < NN) { posArr[seq[gid]] = gid; invNumD[gid] = 1.0f / numNei[gid]; revCntD[gid] = 0; }
  if (gid < 512) {   // pack Wn MFMA B-fragments
    int st = gid >> 6, lane = gid & 63;
    int s = st >> 2, t = st & 3;
    int row = 16*t + (lane & 15);
    int k0 = 32*s + 8*(lane >> 4);
    const float* wr = &Wn[row*64 + k0];
    uint4 f;
    f.x = (unsigned)bf16r(wr[0]) | ((unsigned)bf16r(wr[1]) << 16);
    f.y = (unsigned)bf16r(wr[2]) | ((unsigned)bf16r(wr[3]) << 16);
    f.z = (unsigned)bf16r(wr[4]) | ((unsigned)bf16r(wr[5]) << 16);
    f.w = (unsigned)bf16r(wr[6]) | ((unsigned)bf16r(wr[7]) << 16);
    WnFragD[st*64 + lane] = f;
  }
  for (int e2 = gid; e2 < NN*CAP; e2 += 256*256) lowNeiD[e2] = SENT;
  // per-node GEMV: thread d streams weight row d contiguously
  int w = tid >> 6, d = tid & 63;
  int i = blockIdx.x * 4 + w;
  x_l[w][d]  = inputs[i*DD + d];
  hh_l[w][d] = h0[i*DD + d];
  __syncthreads();
  float afs = bs[d], apre = bg[d], ag0 = 0.0f;
  const float4* wsr = (const float4*)&Ws[d*64];
  const float4* wnr = (const float4*)&Wn[d*64];
  const float4* wga = (const float4*)&Wg[d*128];
  const float4* wgb = (const float4*)&Wg[d*128 + 64];
  #pragma unroll 4
  for (int k4 = 0; k4 < 16; ++k4) {
    float4 ws4 = wsr[k4], wn4 = wnr[k4], wa4 = wga[k4], wb4 = wgb[k4];
    const float* wsp = (const float*)&ws4;
    const float* wnp = (const float*)&wn4;
    const float* wap = (const float*)&wa4;
    const float* wbp = (const float*)&wb4;
    #pragma unroll
    for (int j = 0; j < 4; ++j) {
      int k = 4*k4 + j;
      float xk = x_l[w][k], hk = hh_l[w][k];
      afs  += xk * wsp[j];
      ag0  += hk * wnp[j];
      apre += xk * wap[j] + hk * wbp[j];
    }
  }
  FSd[i*DD + d]      = afs;
  Gd[i*DD + d]       = ag0;
  preBaseD[i*DD + d] = apre;
  fpreD[i*DD + d]    = sigm(afs + ag0);
}

// ---- K2: split neighbors; fold future; LANE-PARALLEL reverse-edge scatter ----
__global__ __launch_bounds__(256) void k_edges(const float* __restrict__ adj,
                                               const float* __restrict__ c0) {
  int tid = threadIdx.x;
  int w = tid >> 6, d = tid & 63;   // d is also this thread's lane id
  int i = blockIdx.x * 4 + w;
  int pi = posArr[i];
  float fs = FSd[i*DD + d];
  float accP = 0.0f, accS = 0.0f;
  int cnt = 0;
  int myj = -1;                     // lane n captures the n-th lower neighbor
  for (int base = 0; base < NN; base += 64) {
    float a = adj[i*NN + base + d];
    unsigned long long mask = __ballot(a != 0.0f);
    while (mask) {
      int b = __ffsll(mask) - 1;
      mask &= (mask - 1);
      int j = base + b;
      if (posArr[j] < pi) {
        if (cnt == d) myj = j;      // uniform cnt, per-lane capture
        cnt++;
      } else {
        float g = Gd[j*DD + d];
        accP += g;
        accS += sigm(fs + g);
      }
    }
  }
  int ccap = (cnt < 64) ? cnt : 64;
  // parallel scatter: one memory latency instead of ~cnt serialized round-trips
  if (d < ccap) {
    lowNeiD[i*CAP + d] = myj << 5;
    int slot = atomicAdd(&revCntD[myj], 1);
    if (slot < RCAP) revNeiD[myj*RCAP + slot] = i;
  }
  float inv = invNumD[i];
  if (d == 0) hdrD[i] = make_int2(ccap, __float_as_int(inv));
  float c0v = c0[i*DD + d];
  float civ = c0v * inv;
  nodeDatD[i*DD + d] = make_float4(NL2E * fs,                 // fs2n = -fs*log2e
                                   preBaseD[i*DD + d] + accP * inv,
                                   civ,
                                   c0v * fpreD[i*DD + d] + civ * accS);
}

// ---- K3: dataflow scheduler; producer-keeps-one continuation; quad-rcp gather ----
__global__ __launch_bounds__(1024, 4) void k_seq(float* __restrict__ out) {
  __shared__ unsigned long long Gl64[(NN*DD + 64)/4];  // bf16 G rows + ZERO dummy row
  __shared__ unsigned low8p[NN][4];
  __shared__ int      queue_[NN];            // packed {node|cnt<<10|rcnt<<17}
  __shared__ int      indeg[NN];             // countdown | cnt<<8 | rcnt<<15
  __shared__ float    invL[NN];
  __shared__ unsigned short hstage[16][64];
  __shared__ int head, tail, doneCnt;
  unsigned short* Gl = (unsigned short*)Gl64;
  int tid  = threadIdx.x;
  int lane = tid & 63, w = tid >> 6;
  if (tid == 0) { head = 0; tail = 0; doneCnt = 0; }
  queue_[tid] = -1;
  int2 hdr = hdrD[tid];
  int  rc  = revCntD[tid];
  int  cnt0 = hdr.x;
  indeg[tid] = cnt0 | (cnt0 << 8) | (rc << 15);
  invL[tid]  = __int_as_float(hdr.y);
  {
    uint4 a = *(const uint4*)&lowNeiD[tid*CAP];
    uint4 b = *(const uint4*)&lowNeiD[tid*CAP + 4];
    low8p[tid][0] = (a.x & 0xffffu) | (a.y << 16);
    low8p[tid][1] = (a.z & 0xffffu) | (a.w << 16);
    low8p[tid][2] = (b.x & 0xffffu) | (b.y << 16);
    low8p[tid][3] = (b.z & 0xffffu) | (b.w << 16);
  }
  if (tid < 16) Gl64[NN*DD/4 + tid] = 0ull;    // ZERO dummy row
  uint4 fb[2][4];
  #pragma unroll
  for (int s = 0; s < 2; ++s) {
    #pragma unroll
    for (int t = 0; t < 4; ++t)
      fb[s][t] = WnFragD[(s*4 + t)*64 + lane];
  }
  __syncthreads();
  if (cnt0 == 0) {
    int p = __hip_atomic_fetch_add(&tail, 1, __ATOMIC_RELAXED, __HIP_MEMORY_SCOPE_WORKGROUP);
    __hip_atomic_store(&queue_[p], tid | (rc << 17), __ATOMIC_RELEASE, __HIP_MEMORY_SCOPE_WORKGROUP);
  }
  __syncthreads();

  // claim first ticket; blocking pop
  int t0 = 0;
  if (lane == 0) t0 = __hip_atomic_fetch_add(&head, 1, __ATOMIC_RELAXED, __HIP_MEMORY_SCOPE_WORKGROUP);
  int t = __builtin_amdgcn_readfirstlane(t0);
  int e = -1;
  if (t < NN) {
    e = __hip_atomic_load(&queue_[t], __ATOMIC_ACQUIRE, __HIP_MEMORY_SCOPE_WORKGROUP);
    while (e < 0)
      e = __hip_atomic_load(&queue_[t], __ATOMIC_ACQUIRE, __HIP_MEMORY_SCOPE_WORKGROUP);
  } else {
    return;  // never for 16 waves, NN >= 16
  }
  e = __builtin_amdgcn_readfirstlane(e);

  int    i, cnt, rcnt, jb2v, r0, r1;
  float4 nd;
  float  inv;
  uint4  lvv;
  #define ISSUE(E) do {                                               \
    i    = (E) & 1023;                                                \
    cnt  = ((E) >> 10) & 127;                                         \
    rcnt = ((E) >> 17) & 255;                                         \
    nd   = nodeDatD[i*DD + lane];                                     \
    jb2v = lowNeiD[i*CAP + 8 + lane];                                 \
    r0   = (lane < rcnt)      ? revNeiD[i*RCAP + lane]      : -1;     \
    r1   = (lane + 64 < rcnt) ? revNeiD[i*RCAP + 64 + lane] : -1;     \
    inv  = invL[i];                                                   \
    lvv  = *(uint4*)&low8p[i][0];                                     \
  } while (0)
  ISSUE(e);

  for (;;) {
    float fs2n = nd.x;
    float accG = 0.0f, accS = 0.0f;
    // ---- gather: 4-granular static blocks; all reads first, then grouped math ----
    float g[32];
    #define LD(c) __uint_as_float(((unsigned)Gl[((c) << 1) + lane]) << 16)
    if (cnt > 0) {
      g[0]=LD(lvv.x & 0xffffu); g[1]=LD(lvv.x >> 16);
      g[2]=LD(lvv.y & 0xffffu); g[3]=LD(lvv.y >> 16);
    }
    if (cnt > 4) {
      g[4]=LD(lvv.z & 0xffffu); g[5]=LD(lvv.z >> 16);
      g[6]=LD(lvv.w & 0xffffu); g[7]=LD(lvv.w >> 16);
    }
    if (cnt > 8) {
      #pragma unroll
      for (int q = 0; q < 4; ++q) g[8+q]  = LD(__builtin_amdgcn_readlane(jb2v, q));
    }
    if (cnt > 12) {
      #pragma unroll
      for (int q = 0; q < 4; ++q) g[12+q] = LD(__builtin_amdgcn_readlane(jb2v, 4+q));
    }
    if (cnt > 16) {
      #pragma unroll
      for (int q = 0; q < 4; ++q) g[16+q] = LD(__builtin_amdgcn_readlane(jb2v, 8+q));
    }
    if (cnt > 20) {
      #pragma unroll
      for (int q = 0; q < 4; ++q) g[20+q] = LD(__builtin_amdgcn_readlane(jb2v, 12+q));
    }
    if (cnt > 24) {
      #pragma unroll
      for (int q = 0; q < 4; ++q) g[24+q] = LD(__builtin_amdgcn_readlane(jb2v, 16+q));
    }
    if (cnt > 28) {
      #pragma unroll
      for (int q = 0; q < 4; ++q) g[28+q] = LD(__builtin_amdgcn_readlane(jb2v, 20+q));
    }
    // quad: sum of 4 sigmoids with ONE rcp
    auto quad = [&](float ga, float gb, float gc, float gd) {
      float xa = fminf(__builtin_fmaf(ga, NL2E, fs2n), 25.0f);
      float xb = fminf(__builtin_fmaf(gb, NL2E, fs2n), 25.0f);
      float xc = fminf(__builtin_fmaf(gc, NL2E, fs2n), 25.0f);
      float xd = fminf(__builtin_fmaf(gd, NL2E, fs2n), 25.0f);
      float ea = __builtin_amdgcn_exp2f(xa);
      float eb = __builtin_amdgcn_exp2f(xb);
      float ec = __builtin_amdgcn_exp2f(xc);
      float ed = __builtin_amdgcn_exp2f(xd);
      float s0 = ea + eb, n0 = s0 + 2.0f;
      float d0 = __builtin_fmaf(ea, eb, s0) + 1.0f;
      float s1 = ec + ed, n1 = s1 + 2.0f;
      float d1 = __builtin_fmaf(ec, ed, s1) + 1.0f;
      float Nn = __builtin_fmaf(n0, d1, n1 * d0);
      float Dd = d0 * d1;
      accS = __builtin_fmaf(Nn, __builtin_amdgcn_rcpf(Dd), accS);
      accG += (ga + gb) + (gc + gd);
    };
    if (cnt > 0)  quad(g[0],  g[1],  g[2],  g[3]);
    if (cnt > 4)  quad(g[4],  g[5],  g[6],  g[7]);
    if (cnt > 8)  quad(g[8],  g[9],  g[10], g[11]);
    if (cnt > 12) quad(g[12], g[13], g[14], g[15]);
    if (cnt > 16) quad(g[16], g[17], g[18], g[19]);
    if (cnt > 20) quad(g[20], g[21], g[22], g[23]);
    if (cnt > 24) quad(g[24], g[25], g[26], g[27]);
    if (cnt > 28) quad(g[28], g[29], g[30], g[31]);
    if (cnt > 32) {
      for (int base = 32; base < cnt; base += 4) {
        float ga = LD(__builtin_amdgcn_readlane(jb2v, base - 8));
        float gb = LD(__builtin_amdgcn_readlane(jb2v, base - 7));
        float gc = LD(__builtin_amdgcn_readlane(jb2v, base - 6));
        float gd = LD(__builtin_amdgcn_readlane(jb2v, base - 5));
        quad(ga, gb, gc, gd);
      }
    }
    // pad correction: pads read the zero row -> each added sigm(fs) to accS
    {
      int slots = (cnt <= 32) ? ((cnt + 3) & ~3) : (32 + ((cnt - 32 + 3) & ~3));
      float e0   = __builtin_amdgcn_exp2f(fminf(fs2n, 25.0f));
      float sig0 = __builtin_amdgcn_rcpf(1.0f + e0);
      accS -= (float)(slots - cnt) * sig0;
    }
    float pre = nd.y + inv * accG;
    float is  = sigm(pre);
    float hcl = tanhf_(pre);
    float c   = nd.z * accS + nd.w + is * hcl;
    float h   = tanhf_(is * c);
    // save current node's tail state before ISSUE overwrites
    int ic = i, r0c = r0, r1c = r1;
    // ---- G[ic] = h @ Wn^T on the MFMA pipe; publish ----
    hstage[w][lane] = bf16r(h);
    const uint4* hv = (const uint4*)&hstage[w][0];
    uint4 fa0 = hv[lane >> 4];
    uint4 fa1 = hv[4 + (lane >> 4)];
    f32x4 z = {0.f, 0.f, 0.f, 0.f};
    f32x4 a0 = __builtin_amdgcn_mfma_f32_16x16x32_bf16(__builtin_bit_cast(bf16x8, fa0), __builtin_bit_cast(bf16x8, fb[0][0]), z, 0, 0, 0);
    f32x4 a1 = __builtin_amdgcn_mfma_f32_16x16x32_bf16(__builtin_bit_cast(bf16x8, fa0), __builtin_bit_cast(bf16x8, fb[0][1]), z, 0, 0, 0);
    f32x4 a2 = __builtin_amdgcn_mfma_f32_16x16x32_bf16(__builtin_bit_cast(bf16x8, fa0), __builtin_bit_cast(bf16x8, fb[0][2]), z, 0, 0, 0);
    f32x4 a3 = __builtin_amdgcn_mfma_f32_16x16x32_bf16(__builtin_bit_cast(bf16x8, fa0), __builtin_bit_cast(bf16x8, fb[0][3]), z, 0, 0, 0);
    a0 = __builtin_amdgcn_mfma_f32_16x16x32_bf16(__builtin_bit_cast(bf16x8, fa1), __builtin_bit_cast(bf16x8, fb[1][0]), a0, 0, 0, 0);
    a1 = __builtin_amdgcn_mfma_f32_16x16x32_bf16(__builtin_bit_cast(bf16x8, fa1), __builtin_bit_cast(bf16x8, fb[1][1]), a1, 0, 0, 0);
    a2 = __builtin_amdgcn_mfma_f32_16x16x32_bf16(__builtin_bit_cast(bf16x8, fa1), __builtin_bit_cast(bf16x8, fb[1][2]), a2, 0, 0, 0);
    a3 = __builtin_amdgcn_mfma_f32_16x16x32_bf16(__builtin_bit_cast(bf16x8, fa1), __builtin_bit_cast(bf16x8, fb[1][3]), a3, 0, 0, 0);
    float r01 = (lane & 16) ? a1[0] : a0[0];
    float r23 = (lane & 16) ? a3[0] : a2[0];
    float rg  = (lane & 32) ? r23 : r01;
    Gl[(ic << 6) + lane] = bf16r(rg);        // publish
    // ---- notify with producer-keeps-one: lane-parallel RMW, ballot, keep first ----
    int en0 = -1, en1 = -1;
    if (r0c >= 0) {
      int old = __hip_atomic_fetch_add(&indeg[r0c], -1, __ATOMIC_ACQ_REL, __HIP_MEMORY_SCOPE_WORKGROUP);
      if ((old & 0xff) == 1)
        en0 = r0c | (((old >> 8) & 127) << 10) | (((old >> 15) & 255) << 17);
    }
    if (r1c >= 0) {
      int old = __hip_atomic_fetch_add(&indeg[r1c], -1, __ATOMIC_ACQ_REL, __HIP_MEMORY_SCOPE_WORKGROUP);
      if ((old & 0xff) == 1)
        en1 = r1c | (((old >> 8) & 127) << 10) | (((old >> 15) & 255) << 17);
    }
    unsigned long long m0 = __ballot(en0 >= 0);
    unsigned long long m1 = __ballot(en1 >= 0);
    int keepEn = -1, kl = -1, ks = -1;
    if (m0) {
      kl = __ffsll(m0) - 1; ks = 0;
      keepEn = __builtin_amdgcn_readlane(en0, kl);
    } else if (m1) {
      kl = __ffsll(m1) - 1; ks = 1;
      keepEn = __builtin_amdgcn_readlane(en1, kl);
    }
    if (en0 >= 0 && !(ks == 0 && lane == kl)) {
      int p = __hip_atomic_fetch_add(&tail, 1, __ATOMIC_RELAXED, __HIP_MEMORY_SCOPE_WORKGROUP);
      __hip_atomic_store(&queue_[p], en0, __ATOMIC_RELEASE, __HIP_MEMORY_SCOPE_WORKGROUP);
    }
    if (en1 >= 0 && !(ks == 1 && lane == kl)) {
      int p = __hip_atomic_fetch_add(&tail, 1, __ATOMIC_RELAXED, __HIP_MEMORY_SCOPE_WORKGROUP);
      __hip_atomic_store(&queue_[p], en1, __ATOMIC_RELEASE, __HIP_MEMORY_SCOPE_WORKGROUP);
    }
    if (lane == 0)
      __hip_atomic_fetch_add(&doneCnt, 1, __ATOMIC_RELAXED, __HIP_MEMORY_SCOPE_WORKGROUP);
    if (keepEn >= 0) {
      // continue directly with the kept dependent: no push/pop/wake on the chain
      ISSUE(keepEn);
      out[ic*DD + lane] = 2.0f * h;
      continue;
    }
    out[ic*DD + lane] = 2.0f * h;
    // ---- pop path (off the critical chain): claim ticket, spin, doneCnt exit ----
    if (lane == 0) t0 = __hip_atomic_fetch_add(&head, 1, __ATOMIC_RELAXED, __HIP_MEMORY_SCOPE_WORKGROUP);
    t = __builtin_amdgcn_readfirstlane(t0);
    if (t >= NN) break;
    int e3;
    for (;;) {
      e3 = __hip_atomic_load(&queue_[t], __ATOMIC_ACQUIRE, __HIP_MEMORY_SCOPE_WORKGROUP);
      if (e3 >= 0) break;
      if (__hip_atomic_load(&doneCnt, __ATOMIC_RELAXED, __HIP_MEMORY_SCOPE_WORKGROUP) == NN) break;
    }
    if (e3 < 0) break;
    e3 = __builtin_amdgcn_readfirstlane(e3);
    ISSUE(e3);
  }
  #undef LD
  #undef ISSUE
}

extern "C" void kernel_launch(void* const* d_in, const int* in_sizes, int n_in,
                              void* d_out, int out_size, void* d_ws, size_t ws_size,
                              hipStream_t stream) {
  const float* inputs = (const float*)d_in[0];
  const float* adj    = (const float*)d_in[1];
  const float* numNei = (const float*)d_in[2];
  const float* h0     = (const float*)d_in[3];
  const float* c0     = (const float*)d_in[4];
  const float* Wg     = (const float*)d_in[5];
  const float* bg     = (const float*)d_in[6];
  const float* Ws     = (const float*)d_in[7];
  const float* bs     = (const float*)d_in[8];
  const float* Wn     = (const float*)d_in[9];
  const int*   seq    = (const int*)d_in[10];
  float* out = (float*)d_out;

  k_node <<<256, 256, 0, stream>>>(seq, numNei, inputs, h0, Wg, bg, Ws, bs, Wn);
  k_edges<<<256, 256, 0, stream>>>(adj, c0);
  k_seq  <<<1, 1024, 0, stream>>>(out);
}